// Round 9
// baseline (197.101 us; speedup 1.0000x reference)
//
#include <hip/hip_runtime.h>
#include <hip/hip_bf16.h>
#include <stdint.h>

// out[m][n] = (sum_k x[m][k] * W[n][k]) * scale[n]
// M=8192 (B*S), N=4096 (D_OUT), K=4096 (D_IN)
// x fp32, W int32 (harness materializes integer inputs as int32), scale fp32.
// INT8 path: W exact int8; x per-row symmetric int8 (sx=amax/127).
// GEMM via mfma_i32_16x16x64_i8. Dequant: out = acc * sx[row] * scale[col].
// Structure: 256x256 tile, BK=64B, 8 waves 2x4, classic 2-buffer LDS (64 KiB
// -> 2 blocks/CU; cross-block LDS/MFMA anti-phase overlap, m97+m114), per-tile
// vmcnt(0) drain covered by the co-resident block. Conflict-free 64B-row
// swizzle: chunk ^= (row>>1)&3 (both sides). T1 XCD swizzle, T5 setprio.

#define M_TOT 8192
#define N_TOT 4096
#define K_TOT 4096
#define BM 256
#define BN 256
#define BK 64
#define NT (K_TOT / BK)   // 64 k-tiles

typedef int intx4 __attribute__((ext_vector_type(4)));

// ---- x quantization: one block per row ----
__global__ void quant_x_kernel(const float* __restrict__ x,
                               int* __restrict__ q,       // packed i8, 4/int
                               float* __restrict__ xs) {  // [M] dequant scale
  const int row = blockIdx.x;
  const int tid = threadIdx.x;
  const float4* xr = (const float4*)(x + (size_t)row * K_TOT);
  float4 v[4];
#pragma unroll
  for (int j = 0; j < 4; ++j) v[j] = xr[tid + 256 * j];
  float am = 0.f;
#pragma unroll
  for (int j = 0; j < 4; ++j) {
    am = fmaxf(am, fmaxf(fmaxf(fabsf(v[j].x), fabsf(v[j].y)),
                         fmaxf(fabsf(v[j].z), fabsf(v[j].w))));
  }
#pragma unroll
  for (int off = 32; off >= 1; off >>= 1)
    am = fmaxf(am, __shfl_xor(am, off));
  __shared__ float wmax[4];
  if ((tid & 63) == 0) wmax[tid >> 6] = am;
  __syncthreads();
  am = fmaxf(fmaxf(wmax[0], wmax[1]), fmaxf(wmax[2], wmax[3]));
  const float inv = 127.0f / fmaxf(am, 1e-30f);
  int* qo = q + (size_t)row * (K_TOT / 4);
#pragma unroll
  for (int j = 0; j < 4; ++j) {
    int b0 = __float2int_rn(v[j].x * inv);
    int b1 = __float2int_rn(v[j].y * inv);
    int b2 = __float2int_rn(v[j].z * inv);
    int b3 = __float2int_rn(v[j].w * inv);
    qo[tid + 256 * j] =
        (b0 & 255) | ((b1 & 255) << 8) | ((b2 & 255) << 16) | (b3 << 24);
  }
  if (tid == 0) xs[row] = am * (1.0f / 127.0f);
}

// ---- W repack: int32 -> i8 (exact) ----
__global__ void pack_w_kernel(const int4* __restrict__ in, int4* __restrict__ out) {
  const int i = blockIdx.x * blockDim.x + threadIdx.x;  // 16 ints -> 16 bytes
  int4 r0 = in[4 * i], r1 = in[4 * i + 1], r2 = in[4 * i + 2], r3 = in[4 * i + 3];
  int4 o;
  o.x = (r0.x & 255) | ((r0.y & 255) << 8) | ((r0.z & 255) << 16) | (r0.w << 24);
  o.y = (r1.x & 255) | ((r1.y & 255) << 8) | ((r1.z & 255) << 16) | (r1.w << 24);
  o.z = (r2.x & 255) | ((r2.y & 255) << 8) | ((r2.z & 255) << 16) | (r2.w << 24);
  o.w = (r3.x & 255) | ((r3.y & 255) << 8) | ((r3.z & 255) << 16) | (r3.w << 24);
  out[i] = o;
}

// ---- async global->LDS (16B per lane, wave-uniform dest + lane*16) ----
__device__ __forceinline__ void gload_lds16(const void* g, const void* l) {
  const __attribute__((address_space(1))) void* gp =
      reinterpret_cast<const __attribute__((address_space(1))) void*>(
          reinterpret_cast<uintptr_t>(g));
  __attribute__((address_space(3))) void* lp =
      reinterpret_cast<__attribute__((address_space(3))) void*>(
          (uint32_t)reinterpret_cast<uintptr_t>(l));
  __builtin_amdgcn_global_load_lds(gp, lp, 16, 0, 0);
}

#define BAR() __builtin_amdgcn_s_barrier()
#define VMCNT(N) asm volatile("s_waitcnt vmcnt(" #N ")" ::: "memory")

// ---- main GEMM: i8, 256x256 tile, 8 waves (2x4), 2-buffer, 2 blocks/CU ----
__global__ __launch_bounds__(512, 2)
void wq_gemm_kernel(const char* __restrict__ A,     // [M][K] i8 (quantized x)
                    const char* __restrict__ B,     // [N][K] i8 (W rows)
                    const float* __restrict__ XS,   // [M] x dequant scale
                    const float* __restrict__ scale,// [N]
                    float* __restrict__ C) {        // [M][N]
  // double buffer: [buf][256 rows][64 B] per operand = 2 x 16 KiB x 2 = 64 KiB
  __shared__ __align__(16) char As[2][BM * BK];
  __shared__ __align__(16) char Bs[2][BN * BK];

  // XCD-aware block swizzle (nwg=512, divisible by 8)
  const int nb = gridDim.x;
  const int swz = (blockIdx.x & 7) * (nb >> 3) + (blockIdx.x >> 3);
  const int bm = swz >> 4;        // M/BM = 32
  const int bn = swz & 15;        // N/BN = 16

  const int tid = threadIdx.x;
  const int wave = tid >> 6, lane = tid & 63;
  const int wr = wave >> 2, wc = wave & 3;   // 2 x 4 wave grid
  const int l15 = lane & 15, lk = lane >> 4;
  const int wr16l = wr * 16 + l15;
  const int wc16l = wc * 16 + l15;
  // Conflict-free 64B-row swizzle: phys chunk = lk ^ ((row>>1)&3); frag rows
  // have row&15 == l15 and bits1-2 from l15 only.
  const int rchunk = (lk ^ ((l15 >> 1) & 3)) << 4;  // bytes

  intx4 acc[8][4] = {};
  intx4 af[4], bf[4];

  // Staging: one gload = 512 threads x 16B = 128 rows x 64B; 2 per operand
  // per tile. LDS dest linear; global source chunk pre-swizzled (involution):
  // thread writes phys chunk (tid&3) of row srow=tid>>2 -> fetch logical
  // chunk (tid&3) ^ ((srow>>1)&3).
  const int srow = tid >> 2;                     // 0..127
  const int sc = (tid & 3) ^ ((tid >> 3) & 3);   // source 16B chunk
  const char* gA = A + (size_t)(bm * BM + srow) * K_TOT + sc * 16;
  const char* gB = B + (size_t)(bn * BN + srow) * K_TOT + sc * 16;

#define STAGE_A(P, J, KT)                                                 \
  gload_lds16(gA + (size_t)(J) * 128 * K_TOT + (size_t)(KT) * BK,         \
              As[P] + (J) * 8192 + wave * 1024)
#define STAGE_B(P, J, KT)                                                 \
  gload_lds16(gB + (size_t)(J) * 128 * K_TOT + (size_t)(KT) * BK,         \
              Bs[P] + (J) * 8192 + wave * 1024)

#define DS16(BASE, ROW)                                                   \
  *(const intx4*)((BASE) + (ROW) * BK + rchunk)

#define LD_A03(P)                                                         \
  _Pragma("unroll") for (int mi = 0; mi < 4; ++mi)                        \
      af[mi] = DS16(As[P], mi * 32 + wr16l);
#define LD_A47(P)                                                         \
  _Pragma("unroll") for (int mi = 0; mi < 4; ++mi)                        \
      af[mi] = DS16(As[P], (mi + 4) * 32 + wr16l);
#define LD_B(P)                                                           \
  _Pragma("unroll") for (int ni = 0; ni < 4; ++ni)                        \
      bf[ni] = DS16(Bs[P], ni * 64 + wc16l);

  // Half-tile: 4 mi x 4 ni = 16 MFMA (K=64 each).
#define MFMA_H(H)                                                         \
  __builtin_amdgcn_s_setprio(1);                                          \
  _Pragma("unroll") for (int mi2 = 0; mi2 < 4; ++mi2)                     \
  _Pragma("unroll") for (int ni2 = 0; ni2 < 4; ++ni2)                     \
      acc[(H) * 4 + mi2][ni2] = __builtin_amdgcn_mfma_i32_16x16x64_i8(    \
          af[mi2], bf[ni2], acc[(H) * 4 + mi2][ni2], 0, 0, 0);            \
  __builtin_amdgcn_s_setprio(0)

  // Tile t (buf P), stage t+1 into Q (finished being read in tile t-1;
  // safe: peers' reads of Q completed before their MFMA1 lgkm-wait, which
  // precedes the final barrier of t-1 that we passed before issuing).
  // vmcnt(0) drain per tile is covered by the co-resident block (m114).
#define TILE(P, Q, T)                                                     \
  do {                                                                    \
    if ((T) + 1 < NT) {                                                   \
      STAGE_B(Q, 0, (T) + 1); STAGE_B(Q, 1, (T) + 1);                     \
      STAGE_A(Q, 0, (T) + 1); STAGE_A(Q, 1, (T) + 1);                     \
    }                                                                     \
    LD_A03(P);                                                            \
    LD_B(P);                                                              \
    BAR();                                                                \
    MFMA_H(0);                                                            \
    BAR();                                                                \
    LD_A47(P);                                                            \
    if ((T) + 1 < NT) { VMCNT(0); }                                       \
    BAR();                                                                \
    MFMA_H(1);                                                            \
    BAR();                                                                \
  } while (0)

  // ---- prologue: stage t0 -> buf0; certify ----
  STAGE_B(0, 0, 0); STAGE_B(0, 1, 0); STAGE_A(0, 0, 0); STAGE_A(0, 1, 0);
  VMCNT(0);
  BAR();

  // ---- main loop ----
  for (int t = 0; t < NT; t += 2) {
    TILE(0, 1, t);
    TILE(1, 0, t + 1);
  }
#undef TILE

  // ---- epilogue: D mapping col=lane&15, row=(lane>>4)*4+e; dequant ----
  const size_t crow0 = (size_t)bm * BM + wr * 16 + (lk << 2);
  const int ccol0 = bn * BN + wc * 16 + l15;
  float sc4[4];
#pragma unroll
  for (int ni = 0; ni < 4; ++ni) sc4[ni] = scale[ccol0 + ni * 64];
#pragma unroll
  for (int mi = 0; mi < 8; ++mi) {
#pragma unroll
    for (int e = 0; e < 4; ++e) {
      const size_t r = crow0 + (size_t)mi * 32 + e;
      const float xr = XS[r];
#pragma unroll
      for (int ni = 0; ni < 4; ++ni)
        C[r * N_TOT + ccol0 + ni * 64] = (float)acc[mi][ni][e] * xr * sc4[ni];
    }
  }
}

// ---- fallback if workspace too small (insurance; slow but correct) ----
__global__ void naive_kernel(const float* __restrict__ x,
                             const int* __restrict__ w,
                             const float* __restrict__ s,
                             float* __restrict__ out) {
  int m = blockIdx.y;
  int n = blockIdx.x * 256 + threadIdx.x;
  const float* xr = x + (size_t)m * K_TOT;
  const int* wr = w + (size_t)n * K_TOT;
  float acc = 0.f;
  for (int k = 0; k < K_TOT; ++k) acc += xr[k] * (float)wr[k];
  out[(size_t)m * N_TOT + n] = acc * s[n];
}

extern "C" void kernel_launch(void* const* d_in, const int* in_sizes, int n_in,
                              void* d_out, int out_size, void* d_ws, size_t ws_size,
                              hipStream_t stream) {
  const float* x = (const float*)d_in[0];
  const int* w = (const int*)d_in[1];
  const float* scale = (const float*)d_in[2];
  float* out = (float*)d_out;

  const size_t x_elems = (size_t)M_TOT * K_TOT;   // i8 bytes
  const size_t w_elems = (size_t)N_TOT * K_TOT;   // i8 bytes
  const size_t need = x_elems + w_elems + M_TOT * sizeof(float);

  if (ws_size < need) {
    dim3 g(N_TOT / 256, M_TOT);
    naive_kernel<<<g, 256, 0, stream>>>(x, w, scale, out);
    return;
  }

  char* qx = (char*)d_ws;
  char* qw = qx + x_elems;
  float* xs = (float*)(qw + w_elems);

  quant_x_kernel<<<M_TOT, 256, 0, stream>>>(x, (int*)qx, xs);
  pack_w_kernel<<<(int)(w_elems / 16 / 256), 256, 0, stream>>>(
      (const int4*)w, (int4*)qw);

  wq_gemm_kernel<<<(M_TOT / BM) * (N_TOT / BN), 512, 0, stream>>>(
      qx, qw, xs, scale, out);
}

// Round 10
// 180.814 us; speedup vs baseline: 1.0901x; 1.0901x over previous
//
#include <hip/hip_runtime.h>
#include <hip/hip_bf16.h>
#include <stdint.h>

// out[m][n] = (sum_k x[m][k] * W[n][k]) * scale[n]
// M=8192 (B*S), N=4096 (D_OUT), K=4096 (D_IN)
// x fp32, W int32 (harness materializes integer inputs as int32), scale fp32.
// INT8 path: W exact int8; x per-row symmetric int8 (sx=amax/127).
// GEMM via mfma_i32_16x16x64_i8. Dequant: out = acc * sx[row] * scale[col].
// Structure (r8 cadence + r9 swizzle): 256x256 tile, BK=64B, 8 waves 2x4,
// 4-buffer LDS rotation (128 KiB, no in-place staging hazard), 2 phases/tile,
// counted vmcnt(4) before the phase-ending barrier (never 0 mid-loop),
// fresh-buffer ds_reads only after it. Conflict-free 64B-row swizzle
// (HW-verified 0 conflicts): read chunk = lk ^ ((l15>>1)&3), source
// pre-swizzled with the matching involution. T1 XCD swizzle, T5 setprio.

#define M_TOT 8192
#define N_TOT 4096
#define K_TOT 4096
#define BM 256
#define BN 256
#define BK 64
#define NT (K_TOT / BK)   // 64 k-tiles

typedef int intx4 __attribute__((ext_vector_type(4)));

// ---- x quantization: one block per row ----
__global__ void quant_x_kernel(const float* __restrict__ x,
                               int* __restrict__ q,       // packed i8, 4/int
                               float* __restrict__ xs) {  // [M] dequant scale
  const int row = blockIdx.x;
  const int tid = threadIdx.x;
  const float4* xr = (const float4*)(x + (size_t)row * K_TOT);
  float4 v[4];
#pragma unroll
  for (int j = 0; j < 4; ++j) v[j] = xr[tid + 256 * j];
  float am = 0.f;
#pragma unroll
  for (int j = 0; j < 4; ++j) {
    am = fmaxf(am, fmaxf(fmaxf(fabsf(v[j].x), fabsf(v[j].y)),
                         fmaxf(fabsf(v[j].z), fabsf(v[j].w))));
  }
#pragma unroll
  for (int off = 32; off >= 1; off >>= 1)
    am = fmaxf(am, __shfl_xor(am, off));
  __shared__ float wmax[4];
  if ((tid & 63) == 0) wmax[tid >> 6] = am;
  __syncthreads();
  am = fmaxf(fmaxf(wmax[0], wmax[1]), fmaxf(wmax[2], wmax[3]));
  const float inv = 127.0f / fmaxf(am, 1e-30f);
  int* qo = q + (size_t)row * (K_TOT / 4);
#pragma unroll
  for (int j = 0; j < 4; ++j) {
    int b0 = __float2int_rn(v[j].x * inv);
    int b1 = __float2int_rn(v[j].y * inv);
    int b2 = __float2int_rn(v[j].z * inv);
    int b3 = __float2int_rn(v[j].w * inv);
    qo[tid + 256 * j] =
        (b0 & 255) | ((b1 & 255) << 8) | ((b2 & 255) << 16) | (b3 << 24);
  }
  if (tid == 0) xs[row] = am * (1.0f / 127.0f);
}

// ---- W repack: int32 -> i8 (exact) ----
__global__ void pack_w_kernel(const int4* __restrict__ in, int4* __restrict__ out) {
  const int i = blockIdx.x * blockDim.x + threadIdx.x;  // 16 ints -> 16 bytes
  int4 r0 = in[4 * i], r1 = in[4 * i + 1], r2 = in[4 * i + 2], r3 = in[4 * i + 3];
  int4 o;
  o.x = (r0.x & 255) | ((r0.y & 255) << 8) | ((r0.z & 255) << 16) | (r0.w << 24);
  o.y = (r1.x & 255) | ((r1.y & 255) << 8) | ((r1.z & 255) << 16) | (r1.w << 24);
  o.z = (r2.x & 255) | ((r2.y & 255) << 8) | ((r2.z & 255) << 16) | (r2.w << 24);
  o.w = (r3.x & 255) | ((r3.y & 255) << 8) | ((r3.z & 255) << 16) | (r3.w << 24);
  out[i] = o;
}

// ---- async global->LDS (16B per lane, wave-uniform dest + lane*16) ----
__device__ __forceinline__ void gload_lds16(const void* g, const void* l) {
  const __attribute__((address_space(1))) void* gp =
      reinterpret_cast<const __attribute__((address_space(1))) void*>(
          reinterpret_cast<uintptr_t>(g));
  __attribute__((address_space(3))) void* lp =
      reinterpret_cast<__attribute__((address_space(3))) void*>(
          (uint32_t)reinterpret_cast<uintptr_t>(l));
  __builtin_amdgcn_global_load_lds(gp, lp, 16, 0, 0);
}

#define BAR() __builtin_amdgcn_s_barrier()
#define VMCNT(N) asm volatile("s_waitcnt vmcnt(" #N ")" ::: "memory")

// ---- main GEMM: i8, 256x256 tile, 8 waves (2x4), 4-buffer rotation ----
__global__ __launch_bounds__(512, 2)
void wq_gemm_kernel(const char* __restrict__ A,     // [M][K] i8 (quantized x)
                    const char* __restrict__ B,     // [N][K] i8 (W rows)
                    const float* __restrict__ XS,   // [M] x dequant scale
                    const float* __restrict__ scale,// [N]
                    float* __restrict__ C) {        // [M][N]
  // 4-buffer rotation: [buf][256 rows][64 B] per operand = 4 x 16 KiB x 2.
  __shared__ __align__(16) char As[4][BM * BK];
  __shared__ __align__(16) char Bs[4][BN * BK];

  // XCD-aware block swizzle (nwg=512, divisible by 8)
  const int nb = gridDim.x;
  const int swz = (blockIdx.x & 7) * (nb >> 3) + (blockIdx.x >> 3);
  const int bm = swz >> 4;        // M/BM = 32
  const int bn = swz & 15;        // N/BN = 16

  const int tid = threadIdx.x;
  const int wave = tid >> 6, lane = tid & 63;
  const int wr = wave >> 2, wc = wave & 3;   // 2 x 4 wave grid
  const int l15 = lane & 15, lk = lane >> 4;
  const int wr16l = wr * 16 + l15;
  const int wc16l = wc * 16 + l15;
  // Conflict-free 64B-row swizzle (HW-verified 0 conflicts, r9):
  // phys chunk = lk ^ ((row>>1)&3); frag rows have row&15 == l15.
  const int rchunk = (lk ^ ((l15 >> 1) & 3)) << 4;  // bytes

  intx4 acc[8][4] = {};
  intx4 af[4], bf[4];

  // Staging: one gload = 512 threads x 16B = 128 rows x 64B; 2 per operand
  // per tile. LDS dest linear; global source chunk pre-swizzled (involution):
  // thread writes phys chunk (tid&3) of row srow=tid>>2 -> fetch logical
  // chunk (tid&3) ^ ((srow>>1)&3).
  const int srow = tid >> 2;                     // 0..127
  const int sc = (tid & 3) ^ ((tid >> 3) & 3);   // source 16B chunk
  const char* gA = A + (size_t)(bm * BM + srow) * K_TOT + sc * 16;
  const char* gB = B + (size_t)(bn * BN + srow) * K_TOT + sc * 16;

#define STAGE_A(P, J, KT)                                                 \
  gload_lds16(gA + (size_t)(J) * 128 * K_TOT + (size_t)(KT) * BK,         \
              As[P] + (J) * 8192 + wave * 1024)
#define STAGE_B(P, J, KT)                                                 \
  gload_lds16(gB + (size_t)(J) * 128 * K_TOT + (size_t)(KT) * BK,         \
              Bs[P] + (J) * 8192 + wave * 1024)

#define DS16(BASE, ROW)                                                   \
  *(const intx4*)((BASE) + (ROW) * BK + rchunk)

#define LD_A03(P)                                                         \
  _Pragma("unroll") for (int mi = 0; mi < 4; ++mi)                        \
      af[mi] = DS16(As[P], mi * 32 + wr16l);
#define LD_A47(P)                                                         \
  _Pragma("unroll") for (int mi = 0; mi < 4; ++mi)                        \
      af[mi] = DS16(As[P], (mi + 4) * 32 + wr16l);
#define LD_B(P)                                                           \
  _Pragma("unroll") for (int ni = 0; ni < 4; ++ni)                        \
      bf[ni] = DS16(Bs[P], ni * 64 + wc16l);

  // Half-tile: 4 mi x 4 ni = 16 MFMA (K=64 each).
#define MFMA_H(H)                                                         \
  __builtin_amdgcn_s_setprio(1);                                          \
  _Pragma("unroll") for (int mi2 = 0; mi2 < 4; ++mi2)                     \
  _Pragma("unroll") for (int ni2 = 0; ni2 < 4; ++ni2)                     \
      acc[(H) * 4 + mi2][ni2] = __builtin_amdgcn_mfma_i32_16x16x64_i8(    \
          af[mi2], bf[ni2], acc[(H) * 4 + mi2][ni2], 0, 0, 0);            \
  __builtin_amdgcn_s_setprio(0)

  // Tile: ph0 {read A03+B (8), stage B(t+2) (2), BAR, 16 MFMA, BAR}
  //       ph1 {read A47 (4), stage A(t+2) (2), VMCNT(4), BAR, 16 MFMA, BAR}
  // Fresh-buffer reads happen only in the phase AFTER every wave's vmcnt +
  // barrier -> cross-wave staging certified. vmcnt never 0 mid-loop.
#define TILE(P, T)                                                        \
  do {                                                                    \
    LD_A03(P);                                                            \
    LD_B(P);                                                              \
    STAGE_B(((P) + 2) & 3, 0, (T) + 2); STAGE_B(((P) + 2) & 3, 1, (T) + 2);\
    BAR();                                                                \
    MFMA_H(0);                                                            \
    BAR();                                                                \
    LD_A47(P);                                                            \
    STAGE_A(((P) + 2) & 3, 0, (T) + 2); STAGE_A(((P) + 2) & 3, 1, (T) + 2);\
    VMCNT(4);                                                             \
    BAR();                                                                \
    MFMA_H(1);                                                            \
    BAR();                                                                \
  } while (0)

  // ---- prologue: stage t0 -> buf0, t1 -> buf1; certify t0 ----
  STAGE_B(0, 0, 0); STAGE_B(0, 1, 0); STAGE_A(0, 0, 0); STAGE_A(0, 1, 0);
  STAGE_B(1, 0, 1); STAGE_B(1, 1, 1); STAGE_A(1, 0, 1); STAGE_A(1, 1, 1);
  VMCNT(4);
  BAR();

  // ---- main loop: tiles 0..NT-5 stage t+2 unconditionally ----
  for (int t = 0; t + 7 < NT; t += 4) {
    TILE(0, t);
    TILE(1, t + 1);
    TILE(2, t + 2);
    TILE(3, t + 3);
  }
  // tail: tiles NT-4, NT-3 still stage; NT-2 drains; NT-1 plain.
  TILE(0, NT - 4);
  TILE(1, NT - 3);
  // tile NT-2 (buf2): no staging; certify NT-1 with vmcnt(0).
  LD_A03(2); LD_B(2); BAR(); MFMA_H(0); BAR();
  LD_A47(2); VMCNT(0); BAR(); MFMA_H(1); BAR();
  // tile NT-1 (buf3)
  LD_A03(3); LD_B(3); BAR(); MFMA_H(0); BAR();
  LD_A47(3);
  MFMA_H(1);
#undef TILE

  // ---- epilogue: D mapping col=lane&15, row=(lane>>4)*4+e; dequant ----
  const size_t crow0 = (size_t)bm * BM + wr * 16 + (lk << 2);
  const int ccol0 = bn * BN + wc * 16 + l15;
  float sc4[4];
#pragma unroll
  for (int ni = 0; ni < 4; ++ni) sc4[ni] = scale[ccol0 + ni * 64];
#pragma unroll
  for (int mi = 0; mi < 8; ++mi) {
#pragma unroll
    for (int e = 0; e < 4; ++e) {
      const size_t r = crow0 + (size_t)mi * 32 + e;
      const float xr = XS[r];
#pragma unroll
      for (int ni = 0; ni < 4; ++ni)
        C[r * N_TOT + ccol0 + ni * 64] = (float)acc[mi][ni][e] * xr * sc4[ni];
    }
  }
}

// ---- fallback if workspace too small (insurance; slow but correct) ----
__global__ void naive_kernel(const float* __restrict__ x,
                             const int* __restrict__ w,
                             const float* __restrict__ s,
                             float* __restrict__ out) {
  int m = blockIdx.y;
  int n = blockIdx.x * 256 + threadIdx.x;
  const float* xr = x + (size_t)m * K_TOT;
  const int* wr = w + (size_t)n * K_TOT;
  float acc = 0.f;
  for (int k = 0; k < K_TOT; ++k) acc += xr[k] * (float)wr[k];
  out[(size_t)m * N_TOT + n] = acc * s[n];
}

extern "C" void kernel_launch(void* const* d_in, const int* in_sizes, int n_in,
                              void* d_out, int out_size, void* d_ws, size_t ws_size,
                              hipStream_t stream) {
  const float* x = (const float*)d_in[0];
  const int* w = (const int*)d_in[1];
  const float* scale = (const float*)d_in[2];
  float* out = (float*)d_out;

  const size_t x_elems = (size_t)M_TOT * K_TOT;   // i8 bytes
  const size_t w_elems = (size_t)N_TOT * K_TOT;   // i8 bytes
  const size_t need = x_elems + w_elems + M_TOT * sizeof(float);

  if (ws_size < need) {
    dim3 g(N_TOT / 256, M_TOT);
    naive_kernel<<<g, 256, 0, stream>>>(x, w, scale, out);
    return;
  }

  char* qx = (char*)d_ws;
  char* qw = qx + x_elems;
  float* xs = (float*)(qw + w_elems);

  quant_x_kernel<<<M_TOT, 256, 0, stream>>>(x, (int*)qx, xs);
  pack_w_kernel<<<(int)(w_elems / 16 / 256), 256, 0, stream>>>(
      (const int4*)w, (int4*)qw);

  wq_gemm_kernel<<<(M_TOT / BM) * (N_TOT / BN), 512, 0, stream>>>(
      qx, qw, xs, scale, out);
}

// Round 11
// 178.544 us; speedup vs baseline: 1.1039x; 1.0127x over previous
//
#include <hip/hip_runtime.h>
#include <hip/hip_bf16.h>
#include <stdint.h>

// out[m][n] = (sum_k x[m][k] * W[n][k]) * scale[n]
// M=8192 (B*S), N=4096 (D_OUT), K=4096 (D_IN)
// x fp32, W int32 (harness materializes integer inputs as int32), scale fp32.
// INT8 path: W exact int8; x per-row symmetric int8 (sx=amax/127).
// GEMM via mfma_i32_16x16x64_i8. Dequant: out = acc * sx[row] * scale[col].
// Structure: 256x256 tile, BK=64B, 8 waves 2x4, 4-buffer LDS rotation,
// *** ONE barrier per K-tile ***: waves de-phase within the tile body so one
// wave's MFMA burst overlaps another's LDS read storm (intra-block antiphase).
// Hazards: reads of tile T certified by vmcnt(4)+BAR at end of T-1; staging
// into (P+2)&3 separated from its last reads (tile T-2) by the same barrier.
// afL/afH separate register sets so MFMA0 overlaps A47 reads (no WAR).
// Conflict-free 64B-row swizzle (0 conflicts, r9/r10). T1 XCD swizzle, T5.

#define M_TOT 8192
#define N_TOT 4096
#define K_TOT 4096
#define BM 256
#define BN 256
#define BK 64
#define NT (K_TOT / BK)   // 64 k-tiles

typedef int intx4 __attribute__((ext_vector_type(4)));

// ---- x quantization: one block per row ----
__global__ void quant_x_kernel(const float* __restrict__ x,
                               int* __restrict__ q,       // packed i8, 4/int
                               float* __restrict__ xs) {  // [M] dequant scale
  const int row = blockIdx.x;
  const int tid = threadIdx.x;
  const float4* xr = (const float4*)(x + (size_t)row * K_TOT);
  float4 v[4];
#pragma unroll
  for (int j = 0; j < 4; ++j) v[j] = xr[tid + 256 * j];
  float am = 0.f;
#pragma unroll
  for (int j = 0; j < 4; ++j) {
    am = fmaxf(am, fmaxf(fmaxf(fabsf(v[j].x), fabsf(v[j].y)),
                         fmaxf(fabsf(v[j].z), fabsf(v[j].w))));
  }
#pragma unroll
  for (int off = 32; off >= 1; off >>= 1)
    am = fmaxf(am, __shfl_xor(am, off));
  __shared__ float wmax[4];
  if ((tid & 63) == 0) wmax[tid >> 6] = am;
  __syncthreads();
  am = fmaxf(fmaxf(wmax[0], wmax[1]), fmaxf(wmax[2], wmax[3]));
  const float inv = 127.0f / fmaxf(am, 1e-30f);
  int* qo = q + (size_t)row * (K_TOT / 4);
#pragma unroll
  for (int j = 0; j < 4; ++j) {
    int b0 = __float2int_rn(v[j].x * inv);
    int b1 = __float2int_rn(v[j].y * inv);
    int b2 = __float2int_rn(v[j].z * inv);
    int b3 = __float2int_rn(v[j].w * inv);
    qo[tid + 256 * j] =
        (b0 & 255) | ((b1 & 255) << 8) | ((b2 & 255) << 16) | (b3 << 24);
  }
  if (tid == 0) xs[row] = am * (1.0f / 127.0f);
}

// ---- W repack: int32 -> i8 (exact) ----
__global__ void pack_w_kernel(const int4* __restrict__ in, int4* __restrict__ out) {
  const int i = blockIdx.x * blockDim.x + threadIdx.x;  // 16 ints -> 16 bytes
  int4 r0 = in[4 * i], r1 = in[4 * i + 1], r2 = in[4 * i + 2], r3 = in[4 * i + 3];
  int4 o;
  o.x = (r0.x & 255) | ((r0.y & 255) << 8) | ((r0.z & 255) << 16) | (r0.w << 24);
  o.y = (r1.x & 255) | ((r1.y & 255) << 8) | ((r1.z & 255) << 16) | (r1.w << 24);
  o.z = (r2.x & 255) | ((r2.y & 255) << 8) | ((r2.z & 255) << 16) | (r2.w << 24);
  o.w = (r3.x & 255) | ((r3.y & 255) << 8) | ((r3.z & 255) << 16) | (r3.w << 24);
  out[i] = o;
}

// ---- async global->LDS (16B per lane, wave-uniform dest + lane*16) ----
__device__ __forceinline__ void gload_lds16(const void* g, const void* l) {
  const __attribute__((address_space(1))) void* gp =
      reinterpret_cast<const __attribute__((address_space(1))) void*>(
          reinterpret_cast<uintptr_t>(g));
  __attribute__((address_space(3))) void* lp =
      reinterpret_cast<__attribute__((address_space(3))) void*>(
          (uint32_t)reinterpret_cast<uintptr_t>(l));
  __builtin_amdgcn_global_load_lds(gp, lp, 16, 0, 0);
}

#define BAR() __builtin_amdgcn_s_barrier()
#define VMCNT(N) asm volatile("s_waitcnt vmcnt(" #N ")" ::: "memory")

// ---- main GEMM: i8, 256x256 tile, 8 waves (2x4), 1 barrier per k-tile ----
__global__ __launch_bounds__(512, 2)
void wq_gemm_kernel(const char* __restrict__ A,     // [M][K] i8 (quantized x)
                    const char* __restrict__ B,     // [N][K] i8 (W rows)
                    const float* __restrict__ XS,   // [M] x dequant scale
                    const float* __restrict__ scale,// [N]
                    float* __restrict__ C) {        // [M][N]
  // 4-buffer rotation: [buf][256 rows][64 B] per operand = 4 x 16 KiB x 2.
  __shared__ __align__(16) char As[4][BM * BK];
  __shared__ __align__(16) char Bs[4][BN * BK];

  // XCD-aware block swizzle (nwg=512, divisible by 8)
  const int nb = gridDim.x;
  const int swz = (blockIdx.x & 7) * (nb >> 3) + (blockIdx.x >> 3);
  const int bm = swz >> 4;        // M/BM = 32
  const int bn = swz & 15;        // N/BN = 16

  const int tid = threadIdx.x;
  const int wave = tid >> 6, lane = tid & 63;
  const int wr = wave >> 2, wc = wave & 3;   // 2 x 4 wave grid
  const int l15 = lane & 15, lk = lane >> 4;
  const int wr16l = wr * 16 + l15;
  const int wc16l = wc * 16 + l15;
  // Conflict-free 64B-row swizzle (HW-verified 0 conflicts, r9/r10):
  // phys chunk = lk ^ ((row>>1)&3); frag rows have row&15 == l15.
  const int rchunk = (lk ^ ((l15 >> 1) & 3)) << 4;  // bytes

  intx4 acc[8][4] = {};
  intx4 afL[4], afH[4], bf[4];

  // Staging: one gload = 512 threads x 16B = 128 rows x 64B; 2 per operand
  // per tile. LDS dest linear; global source chunk pre-swizzled (involution):
  // thread writes phys chunk (tid&3) of row srow=tid>>2 -> fetch logical
  // chunk (tid&3) ^ ((srow>>1)&3).
  const int srow = tid >> 2;                     // 0..127
  const int sc = (tid & 3) ^ ((tid >> 3) & 3);   // source 16B chunk
  const char* gA = A + (size_t)(bm * BM + srow) * K_TOT + sc * 16;
  const char* gB = B + (size_t)(bn * BN + srow) * K_TOT + sc * 16;

#define STAGE_A(P, J, KT)                                                 \
  gload_lds16(gA + (size_t)(J) * 128 * K_TOT + (size_t)(KT) * BK,         \
              As[P] + (J) * 8192 + wave * 1024)
#define STAGE_B(P, J, KT)                                                 \
  gload_lds16(gB + (size_t)(J) * 128 * K_TOT + (size_t)(KT) * BK,         \
              Bs[P] + (J) * 8192 + wave * 1024)

#define DS16(BASE, ROW)                                                   \
  *(const intx4*)((BASE) + (ROW) * BK + rchunk)

#define LD_A03(P)                                                         \
  _Pragma("unroll") for (int mi = 0; mi < 4; ++mi)                        \
      afL[mi] = DS16(As[P], mi * 32 + wr16l);
#define LD_A47(P)                                                         \
  _Pragma("unroll") for (int mi = 0; mi < 4; ++mi)                        \
      afH[mi] = DS16(As[P], (mi + 4) * 32 + wr16l);
#define LD_B(P)                                                           \
  _Pragma("unroll") for (int ni = 0; ni < 4; ++ni)                        \
      bf[ni] = DS16(Bs[P], ni * 64 + wc16l);

  // Half-tile: 4 mi x 4 ni = 16 MFMA (K=64 each).
#define MFMA_H(AF, H)                                                     \
  __builtin_amdgcn_s_setprio(1);                                          \
  _Pragma("unroll") for (int mi2 = 0; mi2 < 4; ++mi2)                     \
  _Pragma("unroll") for (int ni2 = 0; ni2 < 4; ++ni2)                     \
      acc[(H) * 4 + mi2][ni2] = __builtin_amdgcn_mfma_i32_16x16x64_i8(    \
          AF[mi2], bf[ni2], acc[(H) * 4 + mi2][ni2], 0, 0, 0);            \
  __builtin_amdgcn_s_setprio(0)

  // Tile: {read A03+B, stage B(t+2), MFMA0, read A47 (separate regs, no WAR),
  //        stage A(t+2), MFMA1, vmcnt(4), BAR}. Single barrier per tile:
  // waves de-phase within the body -> MFMA of one wave overlaps ds_reads of
  // its SIMD-mate. vmcnt(4) certifies t+1's 4 stages (in-order retirement);
  // barrier makes it cross-wave before t+1's reads. Never vmcnt(0) mid-loop.
#define TILE(P, T)                                                        \
  do {                                                                    \
    LD_A03(P);                                                            \
    LD_B(P);                                                              \
    STAGE_B(((P) + 2) & 3, 0, (T) + 2); STAGE_B(((P) + 2) & 3, 1, (T) + 2);\
    MFMA_H(afL, 0);                                                       \
    LD_A47(P);                                                            \
    STAGE_A(((P) + 2) & 3, 0, (T) + 2); STAGE_A(((P) + 2) & 3, 1, (T) + 2);\
    MFMA_H(afH, 1);                                                       \
    VMCNT(4);                                                             \
    BAR();                                                                \
  } while (0)

  // ---- prologue: stage t0 -> buf0, t1 -> buf1; certify t0 ----
  STAGE_B(0, 0, 0); STAGE_B(0, 1, 0); STAGE_A(0, 0, 0); STAGE_A(0, 1, 0);
  STAGE_B(1, 0, 1); STAGE_B(1, 1, 1); STAGE_A(1, 0, 1); STAGE_A(1, 1, 1);
  VMCNT(4);
  BAR();

  // ---- main loop: tiles 0..NT-5 stage t+2 unconditionally ----
  for (int t = 0; t + 7 < NT; t += 4) {
    TILE(0, t);
    TILE(1, t + 1);
    TILE(2, t + 2);
    TILE(3, t + 3);
  }
  // tail: NT-4, NT-3 still stage (into bufs 2,3); NT-2 drains; NT-1 plain.
  TILE(0, NT - 4);
  TILE(1, NT - 3);
  // tile NT-2 (buf2): no staging; certify NT-1 with vmcnt(0)+BAR.
  LD_A03(2); LD_B(2);
  MFMA_H(afL, 0);
  LD_A47(2);
  MFMA_H(afH, 1);
  VMCNT(0);
  BAR();
  // tile NT-1 (buf3)
  LD_A03(3); LD_B(3);
  MFMA_H(afL, 0);
  LD_A47(3);
  MFMA_H(afH, 1);
#undef TILE

  // ---- epilogue: D mapping col=lane&15, row=(lane>>4)*4+e; dequant ----
  const size_t crow0 = (size_t)bm * BM + wr * 16 + (lk << 2);
  const int ccol0 = bn * BN + wc * 16 + l15;
  float sc4[4];
#pragma unroll
  for (int ni = 0; ni < 4; ++ni) sc4[ni] = scale[ccol0 + ni * 64];
#pragma unroll
  for (int mi = 0; mi < 8; ++mi) {
#pragma unroll
    for (int e = 0; e < 4; ++e) {
      const size_t r = crow0 + (size_t)mi * 32 + e;
      const float xr = XS[r];
#pragma unroll
      for (int ni = 0; ni < 4; ++ni)
        C[r * N_TOT + ccol0 + ni * 64] = (float)acc[mi][ni][e] * xr * sc4[ni];
    }
  }
}

// ---- fallback if workspace too small (insurance; slow but correct) ----
__global__ void naive_kernel(const float* __restrict__ x,
                             const int* __restrict__ w,
                             const float* __restrict__ s,
                             float* __restrict__ out) {
  int m = blockIdx.y;
  int n = blockIdx.x * 256 + threadIdx.x;
  const float* xr = x + (size_t)m * K_TOT;
  const int* wr = w + (size_t)n * K_TOT;
  float acc = 0.f;
  for (int k = 0; k < K_TOT; ++k) acc += xr[k] * (float)wr[k];
  out[(size_t)m * N_TOT + n] = acc * s[n];
}

extern "C" void kernel_launch(void* const* d_in, const int* in_sizes, int n_in,
                              void* d_out, int out_size, void* d_ws, size_t ws_size,
                              hipStream_t stream) {
  const float* x = (const float*)d_in[0];
  const int* w = (const int*)d_in[1];
  const float* scale = (const float*)d_in[2];
  float* out = (float*)d_out;

  const size_t x_elems = (size_t)M_TOT * K_TOT;   // i8 bytes
  const size_t w_elems = (size_t)N_TOT * K_TOT;   // i8 bytes
  const size_t need = x_elems + w_elems + M_TOT * sizeof(float);

  if (ws_size < need) {
    dim3 g(N_TOT / 256, M_TOT);
    naive_kernel<<<g, 256, 0, stream>>>(x, w, scale, out);
    return;
  }

  char* qx = (char*)d_ws;
  char* qw = qx + x_elems;
  float* xs = (float*)(qw + w_elems);

  quant_x_kernel<<<M_TOT, 256, 0, stream>>>(x, (int*)qx, xs);
  pack_w_kernel<<<(int)(w_elems / 16 / 256), 256, 0, stream>>>(
      (const int4*)w, (int4*)qw);

  wq_gemm_kernel<<<(M_TOT / BM) * (N_TOT / BN), 512, 0, stream>>>(
      qx, qw, xs, scale, out);
}